// Round 5
// baseline (412.228 us; speedup 1.0000x reference)
//
#include <hip/hip_runtime.h>
#include <hip/hip_bf16.h>
#include <math.h>

#define B 64
#define N 512
#define C 1024
#define K_NEIGH 32
// Non-band error budget: |S''-S_true| <= E(fp16 GEMM ~0.15) + q(f16 store ~0.03).
// Need DELTA - window/2 - (E+q) > (E+q): 0.625 - 0.085 - 0.18 = 0.36 > 0.18 OK.
// Band entries get exact fp32 recheck (proven absmax 0.0 in R3/R4).
#define DELTA 0.625f
#define BISECT_ITERS 14
#define NKT (C / 32)
#define SLD 68            // Sl col stride (64 rows + 4 pad), bank-conflict-free

typedef __attribute__((ext_vector_type(8))) _Float16 half8;
typedef __attribute__((ext_vector_type(4))) float f32x4;

__device__ __forceinline__ void async_copy16(void* lds, const void* gmem) {
    __builtin_amdgcn_global_load_lds(
        (const __attribute__((address_space(1))) unsigned int*)gmem,
        (__attribute__((address_space(3))) unsigned int*)lds,
        16, 0, 0);
}

// ---------------------------------------------------------------------------
// Kernel 0: x fp32 -> f16 (RNE), stored in d_out (exactly 64 MB). Streaming.
// ---------------------------------------------------------------------------
__global__ __launch_bounds__(256) void cvt_f16(const float* __restrict__ x,
                                               _Float16* __restrict__ xh) {
    const int t = blockIdx.x * 256 + threadIdx.x;   // 8 f32 per thread
    float4 a = ((const float4*)x)[t * 2];
    float4 b = ((const float4*)x)[t * 2 + 1];
    half8 h;
    h[0] = (_Float16)a.x; h[1] = (_Float16)a.y; h[2] = (_Float16)a.z; h[3] = (_Float16)a.w;
    h[4] = (_Float16)b.x; h[5] = (_Float16)b.y; h[6] = (_Float16)b.z; h[7] = (_Float16)b.w;
    ((half8*)xh)[t] = h;
}

// ---------------------------------------------------------------------------
// Kernel 1 (fused): block = 64 rows x 512 cols of one batch.
// Phase 1: S' = xh * xh^T via f16 MFMA; staging by global_load_lds width-16,
//   double-buffered (2 x 32 KB), one barrier per kt; DMA kt+1 issued after
//   the barrier so it overlaps kt's MFMA.
//   LDS staging layout: 16-row group m at base m*1024; within: qtr q (16B of
//   k) at q*256 + rr*16 -> frag reads conflict-free b128.
// Phase 2: acc -> Sl f16 col-major [col*68 + row] in the same LDS.
// Phase 3: per row (16 rows per wave): ballot bisection, band candidates,
//   grouped exact fp32 dots, exact threshold, masks + dinv.
// ---------------------------------------------------------------------------
__global__ __launch_bounds__(256, 2) void gemm_thresh(
        const _Float16* __restrict__ xh, const float* __restrict__ x,
        unsigned long long* __restrict__ masks, float* __restrict__ dinv) {
    extern __shared__ char smem[];                    // 69632 bytes
    _Float16* Sl = (_Float16*)smem;                   // phase 2/3 view

    const int rg = blockIdx.x;                        // 0..7 row-group of 64
    const int b  = blockIdx.y;
    const int t = threadIdx.x, w = t >> 6, lane = t & 63;
    const int quad = lane >> 4, lid = lane & 15;
    const int wc = w * 128;

    const char* xb = (const char*)(xh + (size_t)b * N * C);   // row stride 2048 B
    const int srow16 = lane & 15;                     // row-within-group
    const int sqtr   = lane >> 4;                     // 16B quarter of the 64B chunk

    f32x4 acc[4][8];
#pragma unroll
    for (int r = 0; r < 4; r++)
#pragma unroll
        for (int c = 0; c < 8; c++)
#pragma unroll
            for (int e = 0; e < 4; e++) acc[r][c][e] = 0.f;

    // prologue: DMA kt=0 into buf 0
#pragma unroll
    for (int i = 0; i < 8; i++) {
        const int m = w * 8 + i;
        const char* src = xb + (size_t)(m * 16 + srow16) * 2048 + sqtr * 16;
        async_copy16(smem + m * 1024 + lane * 16, src);
    }
    __syncthreads();

    for (int kt = 0; kt < NKT; kt++) {
        const int pb = kt & 1;
        if (kt + 1 < NKT) {                           // DMA kt+1 into other buf
            char* dbuf = smem + ((kt + 1) & 1) * 32768;
#pragma unroll
            for (int i = 0; i < 8; i++) {
                const int m = w * 8 + i;
                const char* src = xb + (size_t)(m * 16 + srow16) * 2048
                                  + (kt + 1) * 64 + sqtr * 16;
                async_copy16(dbuf + m * 1024 + lane * 16, src);
            }
        }
        const half8* sb = (const half8*)(smem + pb * 32768);
        half8 vb[8];
#pragma unroll
        for (int c = 0; c < 8; c++) vb[c] = sb[(w * 8 + c) * 64 + quad * 16 + lid];
#pragma unroll
        for (int r = 0; r < 4; r++) {
            half8 va = sb[(rg * 4 + r) * 64 + quad * 16 + lid];
#pragma unroll
            for (int c = 0; c < 8; c++)
                acc[r][c] = __builtin_amdgcn_mfma_f32_16x16x32_f16(va, vb[c], acc[r][c], 0, 0, 0);
        }
        __syncthreads();   // drains in-flight DMA + all waves past reads of pb
    }

    // ---- phase 2: acc -> Sl f16 col-major (overwrites staging) ----
    union H4 { _Float16 h[4]; unsigned long long u; };
#pragma unroll
    for (int r = 0; r < 4; r++) {
#pragma unroll
        for (int c = 0; c < 8; c++) {
            const int col  = wc + c * 16 + lid;
            const int row0 = r * 16 + quad * 4;       // C/D: row=(quad*4+e)
            H4 pk;
            pk.h[0] = (_Float16)acc[r][c][0];
            pk.h[1] = (_Float16)acc[r][c][1];
            pk.h[2] = (_Float16)acc[r][c][2];
            pk.h[3] = (_Float16)acc[r][c][3];
            *(unsigned long long*)(&Sl[col * SLD + row0]) = pk.u;
        }
    }
    __syncthreads();

    // ---- phase 3: 16 rows per wave ----
    const float* xB = x + (size_t)b * N * C;
    for (int lr = w * 16; lr < w * 16 + 16; lr++) {
        float v0[8];
#pragma unroll
        for (int k = 0; k < 8; k++)
            v0[k] = (float)Sl[(lane + 64 * k) * SLD + lr];   // col = lane + 64k

        // bisection: cnt(p)=#{v>p}; invariant cnt(lo)>=32, cnt(hi)<=31
        float lo = -1400.f, hi = 1400.f;
        for (int it = 0; it < BISECT_ITERS; it++) {
            const float mid = 0.5f * (lo + hi);
            int c = 0;
#pragma unroll
            for (int k = 0; k < 8; k++) c += __popcll(__ballot(v0[k] > mid));
            if (c >= K_NEIGH) lo = mid; else hi = mid;
        }
        const float P   = 0.5f * (lo + hi);
        const float hiB = P + DELTA, loB = P - DELTA;

        int cA = 0;
#pragma unroll
        for (int k = 0; k < 8; k++) cA += __popcll(__ballot(v0[k] > hiB));
        const int m_need = K_NEIGH - cA;              // >= 1

        // band candidates (one per lane); col = bit + 64*kq
        int cnt = 0, myj = -1;
#pragma unroll
        for (int kq = 0; kq < 8; kq++) {
            unsigned long long bm = __ballot(v0[kq] >= loB && v0[kq] <= hiB);
            while (bm) {
                int bl = __ffsll(bm) - 1;
                bm &= bm - 1;
                if (cnt == lane) myj = bl + 64 * kq;
                cnt++;
            }
        }
        const int nc = cnt < 64 ? cnt : 64;

        // exact fp32 dots, prefetch-grouped by 4
        const int gi = rg * 64 + lr;                  // row within batch
        const float* xi = xB + (size_t)gi * C;
        float4 ai[4];
#pragma unroll
        for (int q = 0; q < 4; q++) ai[q] = *(const float4*)(xi + q * 256 + lane * 4);

        float ex = -INFINITY;
        for (int g = 0; g < nc; g += 4) {
            float4 bv[4][4];
            int jn[4];
#pragma unroll
            for (int u = 0; u < 4; u++) {
                jn[u] = __shfl(myj, (g + u < nc) ? (g + u) : g);
                const float* xj = xB + (size_t)jn[u] * C;
#pragma unroll
                for (int q = 0; q < 4; q++)
                    bv[u][q] = *(const float4*)(xj + q * 256 + lane * 4);
            }
#pragma unroll
            for (int u = 0; u < 4; u++) {
                if (g + u < nc) {
                    float s = 0.f;
#pragma unroll
                    for (int q = 0; q < 4; q++) {
                        s = fmaf(ai[q].x, bv[u][q].x, s);
                        s = fmaf(ai[q].y, bv[u][q].y, s);
                        s = fmaf(ai[q].z, bv[u][q].z, s);
                        s = fmaf(ai[q].w, bv[u][q].w, s);
                    }
#pragma unroll
                    for (int off = 32; off > 0; off >>= 1) s += __shfl_xor(s, off);
                    if (lane == g + u) ex = s;
                }
            }
        }

        // exact threshold = m_need-th largest band value (tie-correct)
        float val = ex, T = -INFINITY;
        for (int it = 0; it < m_need; it++) {
            float M = val;
#pragma unroll
            for (int off = 32; off > 0; off >>= 1) M = fmaxf(M, __shfl_xor(M, off));
            T = M;
            unsigned long long ball = __ballot(val == M);
            int first = __ffsll(ball) - 1;
            if (lane == first) val = -INFINITY;
        }
        const int dec = (lane < nc && ex >= T) ? 1 : 0;

        // bits: certain-above -> 1; band -> exact decision
        int bits[8];
#pragma unroll
        for (int k = 0; k < 8; k++) bits[k] = (v0[k] > hiB) ? 1 : 0;
        for (int c2 = 0; c2 < nc; c2++) {
            int j = __shfl(myj, c2);
            int d = __shfl(dec, c2);
            if (lane == (j & 63)) {
#pragma unroll
                for (int k = 0; k < 8; k++)
                    if (k == (j >> 6)) bits[k] = d;
            }
        }

        unsigned long long msk[8];
        int deg = 0;
#pragma unroll
        for (int k = 0; k < 8; k++) {
            msk[k] = __ballot(bits[k] != 0);
            deg += __popcll(msk[k]);
        }
        if (lane == 0) {
            const size_t row_g = (size_t)b * N + gi;
#pragma unroll
            for (int k = 0; k < 8; k++) masks[row_g * 8 + k] = msk[k];
            dinv[row_g] = rsqrtf((float)deg);
        }
    }
}

// ---------------------------------------------------------------------------
// Kernel 2: out[b,i,j] = maskbit ? dinv[b,i]*dinv[b,j] : 0  (write-only out)
// ---------------------------------------------------------------------------
__global__ __launch_bounds__(256) void scale_adj(float* __restrict__ Sout,
                                                 const unsigned long long* __restrict__ masks,
                                                 const float* __restrict__ dinv) {
    const int idx = blockIdx.x * 256 + threadIdx.x;   // float4 index
    const int jq = idx & 127;
    const int i  = (idx >> 7) & (N - 1);
    const int b  = idx >> 16;
    const int row = (b << 9) | i;
    const int j0 = jq * 4;

    const unsigned long long mk = masks[(size_t)row * 8 + (j0 >> 6)];
    const float di = dinv[row];
    float4 dj = ((const float4*)dinv)[(b << 7) | jq];

    float4 o;
    o.x = ((mk >> ((j0 + 0) & 63)) & 1ull) ? di * dj.x : 0.f;
    o.y = ((mk >> ((j0 + 1) & 63)) & 1ull) ? di * dj.y : 0.f;
    o.z = ((mk >> ((j0 + 2) & 63)) & 1ull) ? di * dj.z : 0.f;
    o.w = ((mk >> ((j0 + 3) & 63)) & 1ull) ? di * dj.w : 0.f;
    ((float4*)Sout)[idx] = o;
}

// ---------------------------------------------------------------------------
extern "C" void kernel_launch(void* const* d_in, const int* in_sizes, int n_in,
                              void* d_out, int out_size, void* d_ws, size_t ws_size,
                              hipStream_t stream) {
    const float* x = (const float*)d_in[0];
    float* out = (float*)d_out;
    _Float16* xh = (_Float16*)d_out;                 // 64 MB staging for f16 x
    unsigned long long* masks = (unsigned long long*)d_ws;     // B*N*8 u64 = 2MB
    float* dinvp = (float*)(masks + (size_t)B * N * 8);        // B*N floats

    cvt_f16<<<(B * N * C / 8) / 256, 256, 0, stream>>>(x, xh);
    gemm_thresh<<<dim3(8, B), 256, 69632, stream>>>(xh, x, masks, dinvp);
    const int total4 = B * N * N / 4;
    scale_adj<<<total4 / 256, 256, 0, stream>>>(out, masks, dinvp);
}

// Round 6
// 373.038 us; speedup vs baseline: 1.1051x; 1.1051x over previous
//
#include <hip/hip_runtime.h>
#include <hip/hip_bf16.h>
#include <math.h>

#define B 64
#define N 512
#define C 1024
#define K_NEIGH 32
// Non-band error budget: |S''-S_true| <= E(fp16 GEMM ~0.15) + q(f16 store ~0.03).
// Need DELTA - window/2 - (E+q) > (E+q): 0.625 - 0.085 - 0.18 = 0.36 > 0.18 OK.
// Band entries get exact fp32 recheck (proven absmax 0.0 in R3/R4/R5).
#define DELTA 0.625f
#define BISECT_ITERS 14
#define NKT (C / 32)
#define SLD 68            // Sl col stride (64 rows + 4 pad), bank-conflict-free

typedef __attribute__((ext_vector_type(8))) _Float16 half8;
typedef __attribute__((ext_vector_type(4))) float f32x4;

__device__ __forceinline__ void async_copy16(void* lds, const void* gmem) {
    __builtin_amdgcn_global_load_lds(
        (const __attribute__((address_space(1))) unsigned int*)gmem,
        (__attribute__((address_space(3))) unsigned int*)lds,
        16, 0, 0);
}

// ---------------------------------------------------------------------------
// Kernel 0: x fp32 -> f16 (RNE), stored in d_out (exactly 64 MB). Streaming.
// ---------------------------------------------------------------------------
__global__ __launch_bounds__(256) void cvt_f16(const float* __restrict__ x,
                                               _Float16* __restrict__ xh) {
    const int t = blockIdx.x * 256 + threadIdx.x;   // 8 f32 per thread
    float4 a = ((const float4*)x)[t * 2];
    float4 b = ((const float4*)x)[t * 2 + 1];
    half8 h;
    h[0] = (_Float16)a.x; h[1] = (_Float16)a.y; h[2] = (_Float16)a.z; h[3] = (_Float16)a.w;
    h[4] = (_Float16)b.x; h[5] = (_Float16)b.y; h[6] = (_Float16)b.z; h[7] = (_Float16)b.w;
    ((half8*)xh)[t] = h;
}

// ---------------------------------------------------------------------------
// Kernel 1 (fused): block = 64 rows x 512 cols of one batch.
// GRID IS dim3(B, 8): linear block id = b + 64*rg -> XCD = b % 8, so all 8
// row-group blocks of a batch share one XCD's L2 and the 1 MB xh panel is
// fetched from HBM once (R5 had dim3(8,B): 8-way HBM duplication, 610 MB).
// Phase 1: S' = xh * xh^T via f16 MFMA; global_load_lds width-16 staging,
//   double-buffered (2 x 32 KB), one barrier per kt.
// Phase 2: acc -> Sl f16 col-major [col*68 + row] in the same LDS.
// Phase 3: per row (16 rows/wave): ballot bisection, band candidates,
//   grouped exact fp32 dots, exact threshold, masks + dinv.
// ---------------------------------------------------------------------------
__global__ __launch_bounds__(256, 2) void gemm_thresh(
        const _Float16* __restrict__ xh, const float* __restrict__ x,
        unsigned long long* __restrict__ masks, float* __restrict__ dinv) {
    extern __shared__ char smem[];                    // 69632 bytes
    _Float16* Sl = (_Float16*)smem;                   // phase 2/3 view

    const int b  = blockIdx.x;                        // batch (XCD = b % 8)
    const int rg = blockIdx.y;                        // 0..7 row-group of 64
    const int t = threadIdx.x, w = t >> 6, lane = t & 63;
    const int quad = lane >> 4, lid = lane & 15;
    const int wc = w * 128;

    const char* xb = (const char*)(xh + (size_t)b * N * C);   // row stride 2048 B
    const int srow16 = lane & 15;                     // row-within-group
    const int sqtr   = lane >> 4;                     // 16B quarter of the 64B chunk

    f32x4 acc[4][8];
#pragma unroll
    for (int r = 0; r < 4; r++)
#pragma unroll
        for (int c = 0; c < 8; c++)
#pragma unroll
            for (int e = 0; e < 4; e++) acc[r][c][e] = 0.f;

    // prologue: DMA kt=0 into buf 0
#pragma unroll
    for (int i = 0; i < 8; i++) {
        const int m = w * 8 + i;
        const char* src = xb + (size_t)(m * 16 + srow16) * 2048 + sqtr * 16;
        async_copy16(smem + m * 1024 + lane * 16, src);
    }
    __syncthreads();

    for (int kt = 0; kt < NKT; kt++) {
        const int pb = kt & 1;
        if (kt + 1 < NKT) {                           // DMA kt+1 into other buf
            char* dbuf = smem + ((kt + 1) & 1) * 32768;
#pragma unroll
            for (int i = 0; i < 8; i++) {
                const int m = w * 8 + i;
                const char* src = xb + (size_t)(m * 16 + srow16) * 2048
                                  + (kt + 1) * 64 + sqtr * 16;
                async_copy16(dbuf + m * 1024 + lane * 16, src);
            }
        }
        const half8* sb = (const half8*)(smem + pb * 32768);
        half8 vb[8];
#pragma unroll
        for (int c = 0; c < 8; c++) vb[c] = sb[(w * 8 + c) * 64 + quad * 16 + lid];
#pragma unroll
        for (int r = 0; r < 4; r++) {
            half8 va = sb[(rg * 4 + r) * 64 + quad * 16 + lid];
#pragma unroll
            for (int c = 0; c < 8; c++)
                acc[r][c] = __builtin_amdgcn_mfma_f32_16x16x32_f16(va, vb[c], acc[r][c], 0, 0, 0);
        }
        __syncthreads();   // drains in-flight DMA + all waves past reads of pb
    }

    // ---- phase 2: acc -> Sl f16 col-major (overwrites staging) ----
    union H4 { _Float16 h[4]; unsigned long long u; };
#pragma unroll
    for (int r = 0; r < 4; r++) {
#pragma unroll
        for (int c = 0; c < 8; c++) {
            const int col  = wc + c * 16 + lid;
            const int row0 = r * 16 + quad * 4;       // C/D: row=(quad*4+e)
            H4 pk;
            pk.h[0] = (_Float16)acc[r][c][0];
            pk.h[1] = (_Float16)acc[r][c][1];
            pk.h[2] = (_Float16)acc[r][c][2];
            pk.h[3] = (_Float16)acc[r][c][3];
            *(unsigned long long*)(&Sl[col * SLD + row0]) = pk.u;
        }
    }
    __syncthreads();

    // ---- phase 3: 16 rows per wave ----
    const float* xB = x + (size_t)b * N * C;
    for (int lr = w * 16; lr < w * 16 + 16; lr++) {
        float v0[8];
#pragma unroll
        for (int k = 0; k < 8; k++)
            v0[k] = (float)Sl[(lane + 64 * k) * SLD + lr];   // col = lane + 64k

        // bisection: cnt(p)=#{v>p}; invariant cnt(lo)>=32, cnt(hi)<=31
        float lo = -1400.f, hi = 1400.f;
        for (int it = 0; it < BISECT_ITERS; it++) {
            const float mid = 0.5f * (lo + hi);
            int c = 0;
#pragma unroll
            for (int k = 0; k < 8; k++) c += __popcll(__ballot(v0[k] > mid));
            if (c >= K_NEIGH) lo = mid; else hi = mid;
        }
        const float P   = 0.5f * (lo + hi);
        const float hiB = P + DELTA, loB = P - DELTA;

        int cA = 0;
#pragma unroll
        for (int k = 0; k < 8; k++) cA += __popcll(__ballot(v0[k] > hiB));
        const int m_need = K_NEIGH - cA;              // >= 1

        // band candidates (one per lane); col = bit + 64*kq
        int cnt = 0, myj = -1;
#pragma unroll
        for (int kq = 0; kq < 8; kq++) {
            unsigned long long bm = __ballot(v0[kq] >= loB && v0[kq] <= hiB);
            while (bm) {
                int bl = __ffsll(bm) - 1;
                bm &= bm - 1;
                if (cnt == lane) myj = bl + 64 * kq;
                cnt++;
            }
        }
        const int nc = cnt < 64 ? cnt : 64;

        // exact fp32 dots, prefetch-grouped by 4
        const int gi = rg * 64 + lr;                  // row within batch
        const float* xi = xB + (size_t)gi * C;
        float4 ai[4];
#pragma unroll
        for (int q = 0; q < 4; q++) ai[q] = *(const float4*)(xi + q * 256 + lane * 4);

        float ex = -INFINITY;
        for (int g = 0; g < nc; g += 4) {
            float4 bv[4][4];
            int jn[4];
#pragma unroll
            for (int u = 0; u < 4; u++) {
                jn[u] = __shfl(myj, (g + u < nc) ? (g + u) : g);
                const float* xj = xB + (size_t)jn[u] * C;
#pragma unroll
                for (int q = 0; q < 4; q++)
                    bv[u][q] = *(const float4*)(xj + q * 256 + lane * 4);
            }
#pragma unroll
            for (int u = 0; u < 4; u++) {
                if (g + u < nc) {
                    float s = 0.f;
#pragma unroll
                    for (int q = 0; q < 4; q++) {
                        s = fmaf(ai[q].x, bv[u][q].x, s);
                        s = fmaf(ai[q].y, bv[u][q].y, s);
                        s = fmaf(ai[q].z, bv[u][q].z, s);
                        s = fmaf(ai[q].w, bv[u][q].w, s);
                    }
#pragma unroll
                    for (int off = 32; off > 0; off >>= 1) s += __shfl_xor(s, off);
                    if (lane == g + u) ex = s;
                }
            }
        }

        // exact threshold = m_need-th largest band value (tie-correct)
        float val = ex, T = -INFINITY;
        for (int it = 0; it < m_need; it++) {
            float M = val;
#pragma unroll
            for (int off = 32; off > 0; off >>= 1) M = fmaxf(M, __shfl_xor(M, off));
            T = M;
            unsigned long long ball = __ballot(val == M);
            int first = __ffsll(ball) - 1;
            if (lane == first) val = -INFINITY;
        }
        const int dec = (lane < nc && ex >= T) ? 1 : 0;

        // bits: certain-above -> 1; band -> exact decision
        int bits[8];
#pragma unroll
        for (int k = 0; k < 8; k++) bits[k] = (v0[k] > hiB) ? 1 : 0;
        for (int c2 = 0; c2 < nc; c2++) {
            int j = __shfl(myj, c2);
            int d = __shfl(dec, c2);
            if (lane == (j & 63)) {
#pragma unroll
                for (int k = 0; k < 8; k++)
                    if (k == (j >> 6)) bits[k] = d;
            }
        }

        unsigned long long msk[8];
        int deg = 0;
#pragma unroll
        for (int k = 0; k < 8; k++) {
            msk[k] = __ballot(bits[k] != 0);
            deg += __popcll(msk[k]);
        }
        if (lane == 0) {
            const size_t row_g = (size_t)b * N + gi;
#pragma unroll
            for (int k = 0; k < 8; k++) masks[row_g * 8 + k] = msk[k];
            dinv[row_g] = rsqrtf((float)deg);
        }
    }
}

// ---------------------------------------------------------------------------
// Kernel 2: out[b,i,j] = maskbit ? dinv[b,i]*dinv[b,j] : 0  (write-only out)
// ---------------------------------------------------------------------------
__global__ __launch_bounds__(256) void scale_adj(float* __restrict__ Sout,
                                                 const unsigned long long* __restrict__ masks,
                                                 const float* __restrict__ dinv) {
    const int idx = blockIdx.x * 256 + threadIdx.x;   // float4 index
    const int jq = idx & 127;
    const int i  = (idx >> 7) & (N - 1);
    const int b  = idx >> 16;
    const int row = (b << 9) | i;
    const int j0 = jq * 4;

    const unsigned long long mk = masks[(size_t)row * 8 + (j0 >> 6)];
    const float di = dinv[row];
    float4 dj = ((const float4*)dinv)[(b << 7) | jq];

    float4 o;
    o.x = ((mk >> ((j0 + 0) & 63)) & 1ull) ? di * dj.x : 0.f;
    o.y = ((mk >> ((j0 + 1) & 63)) & 1ull) ? di * dj.y : 0.f;
    o.z = ((mk >> ((j0 + 2) & 63)) & 1ull) ? di * dj.z : 0.f;
    o.w = ((mk >> ((j0 + 3) & 63)) & 1ull) ? di * dj.w : 0.f;
    ((float4*)Sout)[idx] = o;
}

// ---------------------------------------------------------------------------
extern "C" void kernel_launch(void* const* d_in, const int* in_sizes, int n_in,
                              void* d_out, int out_size, void* d_ws, size_t ws_size,
                              hipStream_t stream) {
    const float* x = (const float*)d_in[0];
    float* out = (float*)d_out;
    _Float16* xh = (_Float16*)d_out;                 // 64 MB staging for f16 x
    unsigned long long* masks = (unsigned long long*)d_ws;     // B*N*8 u64 = 2MB
    float* dinvp = (float*)(masks + (size_t)B * N * 8);        // B*N floats

    cvt_f16<<<(B * N * C / 8) / 256, 256, 0, stream>>>(x, xh);
    gemm_thresh<<<dim3(B, 8), 256, 69632, stream>>>(xh, x, masks, dinvp);
    const int total4 = B * N * N / 4;
    scale_adj<<<total4 / 256, 256, 0, stream>>>(out, masks, dinvp);
}